// Round 1
// baseline (825.120 us; speedup 1.0000x reference)
//
#include <hip/hip_runtime.h>
#include <math.h>

typedef short short8v __attribute__((ext_vector_type(8)));
typedef float f32x4 __attribute__((ext_vector_type(4)));
typedef unsigned short ushort4v __attribute__((ext_vector_type(4)));

#define T_TOK 8192
#define DDIM 1024
#define HDIM 4096
#define NE 8
#define CCAP 2150
#define CPAD 2176   // 17 * 128

__device__ __forceinline__ unsigned short f2bf(float f) {
  union { float f; unsigned u; } a; a.f = f;
  unsigned r = a.u + 0x7fffu + ((a.u >> 16) & 1u);   // RNE
  return (unsigned short)(r >> 16);
}
__device__ __forceinline__ float bf2f(unsigned short h) {
  union { unsigned u; float f; } a; a.u = ((unsigned)h) << 16;
  return a.f;
}

#define GLOAD_LDS16(gp, lp)                                                   \
  __builtin_amdgcn_global_load_lds(                                           \
      (const __attribute__((address_space(1))) void*)(gp),                    \
      (__attribute__((address_space(3))) void*)(lp), 16, 0, 0)

// ---------------------------------------------------------------- router ---
__global__ __launch_bounds__(256) void router_kernel(
    const float* __restrict__ x, const float* __restrict__ Wg,
    int2* __restrict__ topi, float2* __restrict__ topv,
    float* __restrict__ blkimp) {
  __shared__ float wg[NE * DDIM];
  __shared__ float gsh[4][NE];
  int tid = threadIdx.x;
  for (int i = tid; i < NE * DDIM / 4; i += 256)
    ((float4*)wg)[i] = ((const float4*)Wg)[i];
  __syncthreads();
  int w = tid >> 6, lane = tid & 63;
  int t = blockIdx.x * 4 + w;
  const float* xr = x + (size_t)t * DDIM;
  float p[NE] = {0.f, 0.f, 0.f, 0.f, 0.f, 0.f, 0.f, 0.f};
#pragma unroll
  for (int j = 0; j < 16; ++j) {
    float xv = xr[lane + 64 * j];
#pragma unroll
    for (int e = 0; e < NE; ++e)
      p[e] = fmaf(xv, wg[e * DDIM + lane + 64 * j], p[e]);
  }
#pragma unroll
  for (int e = 0; e < NE; ++e) {
#pragma unroll
    for (int off = 32; off > 0; off >>= 1) p[e] += __shfl_xor(p[e], off, 64);
  }
  // softmax over 8 (all lanes redundantly, lane-uniform)
  float mx = p[0];
#pragma unroll
  for (int e = 1; e < NE; ++e) mx = fmaxf(mx, p[e]);
  float g[NE];
  float s = 0.f;
#pragma unroll
  for (int e = 0; e < NE; ++e) { g[e] = expf(p[e] - mx); s += g[e]; }
  float inv = 1.0f / s;
#pragma unroll
  for (int e = 0; e < NE; ++e) g[e] *= inv;
  // top-2, ties -> lowest index (lax.top_k semantics)
  int i0 = 0; float v0 = g[0];
#pragma unroll
  for (int e = 1; e < NE; ++e) if (g[e] > v0) { v0 = g[e]; i0 = e; }
  int i1 = -1; float v1 = -1.0f;
#pragma unroll
  for (int e = 0; e < NE; ++e)
    if (e != i0 && g[e] > v1) { v1 = g[e]; i1 = e; }
  if (lane == 0) {
    topi[t] = make_int2(i0, i1);
    topv[t] = make_float2(v0, v1);
#pragma unroll
    for (int e = 0; e < NE; ++e) gsh[w][e] = g[e];
  }
  __syncthreads();
  if (tid < NE)
    blkimp[blockIdx.x * NE + tid] =
        gsh[0][tid] + gsh[1][tid] + gsh[2][tid] + gsh[3][tid];
}

// ---------------------------------------------- FCFS dispatch + losses -----
__global__ __launch_bounds__(256) void dispatch_kernel(
    const int2* __restrict__ topi, const float2* __restrict__ topv,
    const float* __restrict__ blkimp, int2* __restrict__ posmj,
    float2* __restrict__ wmaj, float* __restrict__ tail) {
  __shared__ unsigned char eid[2 * T_TOK];
  __shared__ unsigned short possm[2 * T_TOK];
  __shared__ int cnt_sh[NE];
  __shared__ float part[32][NE];
  int tid = threadIdx.x;
  for (int i = tid; i < T_TOK; i += 256) {
    int2 ti = topi[i];
    eid[i] = (unsigned char)ti.x;          // slot 0, token-major
    eid[T_TOK + i] = (unsigned char)ti.y;  // slot 1
  }
  __syncthreads();
  if (tid < 64) {  // wave-0 sequential slot-major scan, 64 entries/step
    int lane = tid;
    unsigned long long low = (1ull << lane) - 1ull;
    int c0 = 0, c1 = 0, c2 = 0, c3 = 0, c4 = 0, c5 = 0, c6 = 0, c7 = 0;
    for (int base = 0; base < 2 * T_TOK; base += 64) {
      int e = eid[base + lane];
      unsigned long long m0 = __ballot(e == 0);
      unsigned long long m1 = __ballot(e == 1);
      unsigned long long m2 = __ballot(e == 2);
      unsigned long long m3 = __ballot(e == 3);
      unsigned long long m4 = __ballot(e == 4);
      unsigned long long m5 = __ballot(e == 5);
      unsigned long long m6 = __ballot(e == 6);
      unsigned long long m7 = __ballot(e == 7);
      int rank = 0;
      if (e == 0) rank = c0 + __popcll(m0 & low);
      if (e == 1) rank = c1 + __popcll(m1 & low);
      if (e == 2) rank = c2 + __popcll(m2 & low);
      if (e == 3) rank = c3 + __popcll(m3 & low);
      if (e == 4) rank = c4 + __popcll(m4 & low);
      if (e == 5) rank = c5 + __popcll(m5 & low);
      if (e == 6) rank = c6 + __popcll(m6 & low);
      if (e == 7) rank = c7 + __popcll(m7 & low);
      possm[base + lane] = (unsigned short)((rank < CCAP) ? rank : CCAP);
      c0 += __popcll(m0); c1 += __popcll(m1); c2 += __popcll(m2);
      c3 += __popcll(m3); c4 += __popcll(m4); c5 += __popcll(m5);
      c6 += __popcll(m6); c7 += __popcll(m7);
    }
    if (lane == 0) {
      cnt_sh[0] = c0; cnt_sh[1] = c1; cnt_sh[2] = c2; cnt_sh[3] = c3;
      cnt_sh[4] = c4; cnt_sh[5] = c5; cnt_sh[6] = c6; cnt_sh[7] = c7;
    }
  }
  __syncthreads();
  for (int t = tid; t < T_TOK; t += 256) {
    int p0 = possm[t], p1 = possm[T_TOK + t];
    float2 tv = topv[t];
    float w0 = (p0 < CCAP) ? tv.x : 0.0f;
    float w1 = (p1 < CCAP) ? tv.y : 0.0f;
    float s = w0 + w1;
    if (s > 0.0f) { w0 /= s; w1 /= s; }
    posmj[t] = make_int2(p0, p1);
    wmaj[t] = make_float2(w0, w1);
  }
  {  // deterministic importance reduction: 2048 blocks x 8 experts
    int sl = tid >> 3, e8 = tid & 7;
    float s = 0.f;
    for (int b = sl; b < 2048; b += 32) s += blkimp[b * NE + e8];
    part[sl][e8] = s;
  }
  __syncthreads();
  if (tid == 0) {
    float imp[NE], te[NE];
    for (int e = 0; e < NE; ++e) {
      float s = 0.f;
      for (int j = 0; j < 32; ++j) s += part[j][e];
      imp[e] = s;
      int c = cnt_sh[e];
      te[e] = (float)(c < CCAP ? c : CCAP);
    }
    float mi = 0.f, mt = 0.f;
    for (int e = 0; e < NE; ++e) { mi += imp[e]; mt += te[e]; }
    mi *= 0.125f; mt *= 0.125f;
    float vi = 0.f, vt = 0.f;
    for (int e = 0; e < NE; ++e) {
      vi += (imp[e] - mi) * (imp[e] - mi);
      vt += (te[e] - mt) * (te[e] - mt);
    }
    vi *= 0.125f; vt *= 0.125f;
    float ai = sqrtf(vi) / (mi + 1e-6f);
    float at = sqrtf(vt) / (mt + 1e-6f);
    float l_imp = ai * ai, l_load = at * at;
    tail[0] = 0.5f * (l_imp + l_load);
    tail[1] = l_load;
  }
}

// --------------------------------------------------------------- scatter ---
__global__ __launch_bounds__(256) void scatter_kernel(
    const float* __restrict__ x, const int2* __restrict__ topi,
    const int2* __restrict__ posmj, unsigned short* __restrict__ ein) {
  int tid = threadIdx.x;
  int gid = blockIdx.x * 4 + (tid >> 6);  // entry id (t,k)
  int lane = tid & 63;
  int t = gid >> 1, k = gid & 1;
  int2 pp = posmj[t];
  int p = k ? pp.y : pp.x;
  if (p >= CCAP) return;
  int2 ii = topi[t];
  int e = k ? ii.y : ii.x;
  const float4* src = (const float4*)(x + (size_t)t * DDIM);
  unsigned short* dst = ein + ((size_t)e * CPAD + p) * DDIM;
#pragma unroll
  for (int j = 0; j < 4; ++j) {
    int c = j * 64 + lane;
    float4 v = src[c];
    ushort4v o;
    o.x = f2bf(v.x); o.y = f2bf(v.y); o.z = f2bf(v.z); o.w = f2bf(v.w);
    *(ushort4v*)(dst + (size_t)c * 4) = o;
  }
}

// ------------------------------------------------- weight transpose+cvt ----
// W: (E, R, Cc) f32 -> WT: (E, Cc, R) bf16
__global__ __launch_bounds__(256) void transpose_cvt_kernel(
    const float* __restrict__ W, unsigned short* __restrict__ WT, int R,
    int Cc) {
  __shared__ unsigned short tile[64][72];
  int rt = R >> 6, ct = Cc >> 6;
  int per_e = rt * ct;
  int e = blockIdx.x / per_e;
  int rem = blockIdx.x % per_e;
  int tr = rem % rt, tc = rem / rt;
  int r0 = tr << 6, c0 = tc << 6;
  const float* We = W + (size_t)e * R * Cc;
  unsigned short* WTe = WT + (size_t)e * R * Cc;
  int tid = threadIdx.x;
  {
    int rl = tid >> 2, cb = (tid & 3) << 4;
    const float* src = We + (size_t)(r0 + rl) * Cc + c0 + cb;
#pragma unroll
    for (int j = 0; j < 16; j += 4) {
      float4 v = *(const float4*)(src + j);
      tile[rl][cb + j + 0] = f2bf(v.x);
      tile[rl][cb + j + 1] = f2bf(v.y);
      tile[rl][cb + j + 2] = f2bf(v.z);
      tile[rl][cb + j + 3] = f2bf(v.w);
    }
  }
  __syncthreads();
  {
    int cl = tid >> 2, rb = (tid & 3) << 4;
    unsigned short* dst = WTe + (size_t)(c0 + cl) * R + r0 + rb;
#pragma unroll
    for (int j = 0; j < 16; j += 4) {
      ushort4v o;
      o.x = tile[rb + j + 0][cl];
      o.y = tile[rb + j + 1][cl];
      o.z = tile[rb + j + 2][cl];
      o.w = tile[rb + j + 3][cl];
      *(ushort4v*)(dst + j) = o;
    }
  }
}

// ------------------------------------------------------- grouped GEMM ------
// A: (E, M, K) bf16 row-major; B: (E, N, K) bf16 (i.e. B^T, K contiguous);
// Out: (E, M, N).  128x128 tile, BK=64, 4 waves (2x2), 16x16x32 bf16 MFMA.
template <bool GELU, bool OUT_BF16>
__global__ __launch_bounds__(256) void gemm_bt_kernel(
    const unsigned short* __restrict__ A, const unsigned short* __restrict__ B,
    const float* __restrict__ bias, void* __restrict__ Out, int M, int N,
    int K) {
  constexpr int BM = 128, BN = 128, BK = 64;
  __shared__ __align__(16) unsigned short As[BM * BK];
  __shared__ __align__(16) unsigned short Bs[BN * BK];
  int mt = M / BM, nt = N / BN;
  int per_e = mt * nt;
  int e = blockIdx.x / per_e;
  int rem = blockIdx.x % per_e;
  int bm = rem % mt, bn = rem / mt;
  size_t Kz = (size_t)K;
  const unsigned short* Ae = A + ((size_t)e * M + (size_t)bm * BM) * Kz;
  const unsigned short* Be = B + ((size_t)e * N + (size_t)bn * BN) * Kz;
  int tid = threadIdx.x;
  int lane = tid & 63;
  int w = tid >> 6;
  int wr = (w >> 1) << 6;   // wave row origin in tile
  int wc = (w & 1) << 6;    // wave col origin
  int fr = lane & 15;
  int fo = (lane >> 4) << 3;

  f32x4 acc[4][4] = {};

  for (int k0 = 0; k0 < K; k0 += BK) {
    __syncthreads();
#pragma unroll
    for (int i = 0; i < 4; ++i) {
      int id16 = i * 256 + tid;     // 16B chunk id, 1024 per tile
      int row = id16 >> 3;          // 8 chunks per 64-elem row
      int c8 = (id16 & 7) << 3;
      GLOAD_LDS16(Ae + (size_t)row * Kz + k0 + c8, As + id16 * 8);
      GLOAD_LDS16(Be + (size_t)row * Kz + k0 + c8, Bs + id16 * 8);
    }
    __syncthreads();
#pragma unroll
    for (int kk = 0; kk < BK; kk += 32) {
      short8v af[4], bfv[4];
#pragma unroll
      for (int m = 0; m < 4; ++m)
        af[m] = *(const short8v*)(As + (wr + m * 16 + fr) * BK + kk + fo);
#pragma unroll
      for (int n = 0; n < 4; ++n)
        bfv[n] = *(const short8v*)(Bs + (wc + n * 16 + fr) * BK + kk + fo);
#pragma unroll
      for (int m = 0; m < 4; ++m)
#pragma unroll
        for (int n = 0; n < 4; ++n)
          acc[m][n] = __builtin_amdgcn_mfma_f32_16x16x32_bf16(
              af[m], bfv[n], acc[m][n], 0, 0, 0);
    }
  }

  const float* be_ = bias + (size_t)e * N + (size_t)bn * BN;
  size_t obase = ((size_t)e * M + (size_t)bm * BM) * (size_t)N + (size_t)bn * BN;
#pragma unroll
  for (int m = 0; m < 4; ++m) {
    int r0 = wr + m * 16 + ((lane >> 4) << 2);
#pragma unroll
    for (int j = 0; j < 4; ++j) {
      size_t rowoff = obase + (size_t)(r0 + j) * N;
#pragma unroll
      for (int n = 0; n < 4; ++n) {
        int col = wc + n * 16 + fr;
        float v = acc[m][n][j] + be_[col];
        if (GELU) v = 0.5f * v * (1.0f + erff(v * 0.70710678118654752f));
        if (OUT_BF16)
          ((unsigned short*)Out)[rowoff + col] = f2bf(v);
        else
          ((float*)Out)[rowoff + col] = v;
      }
    }
  }
}

// ---------------------------------------------------------------- gather ---
__global__ __launch_bounds__(256) void gather_kernel(
    const unsigned short* __restrict__ obuf, const int2* __restrict__ topi,
    const int2* __restrict__ posmj, const float2* __restrict__ wmaj,
    float* __restrict__ y) {
  int tid = threadIdx.x;
  int w = tid >> 6, lane = tid & 63;
  int t = blockIdx.x * 4 + w;
  int2 pp = posmj[t];
  int2 ii = topi[t];
  float2 ww = wmaj[t];
  float* yr = y + (size_t)t * DDIM;
  const unsigned short* s0 =
      (pp.x < CCAP) ? obuf + ((size_t)ii.x * CPAD + pp.x) * DDIM : nullptr;
  const unsigned short* s1 =
      (pp.y < CCAP) ? obuf + ((size_t)ii.y * CPAD + pp.y) * DDIM : nullptr;
#pragma unroll
  for (int j = 0; j < 4; ++j) {
    int c = j * 64 + lane;
    float ax = 0.f, ay = 0.f, az = 0.f, aw = 0.f;
    if (s0) {
      ushort4v a = *(const ushort4v*)(s0 + (size_t)c * 4);
      ax += ww.x * bf2f(a.x); ay += ww.x * bf2f(a.y);
      az += ww.x * bf2f(a.z); aw += ww.x * bf2f(a.w);
    }
    if (s1) {
      ushort4v b = *(const ushort4v*)(s1 + (size_t)c * 4);
      ax += ww.y * bf2f(b.x); ay += ww.y * bf2f(b.y);
      az += ww.y * bf2f(b.z); aw += ww.y * bf2f(b.w);
    }
    ((float4*)yr)[c] = make_float4(ax, ay, az, aw);
  }
}

// ---------------------------------------------------------------------------
extern "C" void kernel_launch(void* const* d_in, const int* in_sizes, int n_in,
                              void* d_out, int out_size, void* d_ws,
                              size_t ws_size, hipStream_t stream) {
  (void)in_sizes; (void)n_in; (void)out_size; (void)ws_size;
  const float* x = (const float*)d_in[0];
  const float* Wg = (const float*)d_in[1];
  const float* W1 = (const float*)d_in[2];
  const float* b1 = (const float*)d_in[3];
  const float* W2 = (const float*)d_in[4];
  const float* b2 = (const float*)d_in[5];
  float* out = (float*)d_out;

  char* ws = (char*)d_ws;
  size_t off = 0;
  auto alloc = [&](size_t b) {
    char* p = ws + off;
    off += (b + 255) & ~(size_t)255;
    return p;
  };
  unsigned short* ein = (unsigned short*)alloc((size_t)NE * CPAD * DDIM * 2);
  unsigned short* hbuf = (unsigned short*)alloc((size_t)NE * CPAD * HDIM * 2);
  unsigned short* obuf = (unsigned short*)alloc((size_t)NE * CPAD * DDIM * 2);
  unsigned short* w1t = (unsigned short*)alloc((size_t)NE * HDIM * DDIM * 2);
  unsigned short* w2t = (unsigned short*)alloc((size_t)NE * DDIM * HDIM * 2);
  int2* topi = (int2*)alloc(T_TOK * sizeof(int2));
  float2* topv = (float2*)alloc(T_TOK * sizeof(float2));
  int2* posmj = (int2*)alloc(T_TOK * sizeof(int2));
  float2* wmaj = (float2*)alloc(T_TOK * sizeof(float2));
  float* blkimp = (float*)alloc(2048 * NE * sizeof(float));

  // weight transpose+convert: W1 (E,D,H)->(E,H,D) bf16 ; W2 (E,H,D)->(E,D,H)
  transpose_cvt_kernel<<<NE * (DDIM / 64) * (HDIM / 64), 256, 0, stream>>>(
      W1, w1t, DDIM, HDIM);
  transpose_cvt_kernel<<<NE * (HDIM / 64) * (DDIM / 64), 256, 0, stream>>>(
      W2, w2t, HDIM, DDIM);
  router_kernel<<<T_TOK / 4, 256, 0, stream>>>(x, Wg, topi, topv, blkimp);
  dispatch_kernel<<<1, 256, 0, stream>>>(topi, topv, blkimp, posmj, wmaj,
                                         out + (size_t)T_TOK * DDIM);
  scatter_kernel<<<(2 * T_TOK) / 4, 256, 0, stream>>>(x, topi, posmj, ein);
  gemm_bt_kernel<true, true>
      <<<NE * (CPAD / 128) * (HDIM / 128), 256, 0, stream>>>(
          ein, w1t, b1, hbuf, CPAD, HDIM, DDIM);
  gemm_bt_kernel<false, true>
      <<<NE * (CPAD / 128) * (DDIM / 128), 256, 0, stream>>>(
          hbuf, w2t, b2, obuf, CPAD, DDIM, HDIM);
  gather_kernel<<<T_TOK / 4, 256, 0, stream>>>(obuf, topi, posmj, wmaj, out);
}

// Round 2
// 683.257 us; speedup vs baseline: 1.2076x; 1.2076x over previous
//
#include <hip/hip_runtime.h>
#include <math.h>

typedef short short8v __attribute__((ext_vector_type(8)));
typedef float f32x4 __attribute__((ext_vector_type(4)));
typedef unsigned short ushort4v __attribute__((ext_vector_type(4)));

#define T_TOK 8192
#define DDIM 1024
#define HDIM 4096
#define NE 8
#define CCAP 2150
#define CPAD 2304   // 9 * 256

__device__ __forceinline__ unsigned short f2bf(float f) {
  union { float f; unsigned u; } a; a.f = f;
  unsigned r = a.u + 0x7fffu + ((a.u >> 16) & 1u);   // RNE
  return (unsigned short)(r >> 16);
}
__device__ __forceinline__ float bf2f(unsigned short h) {
  union { unsigned u; float f; } a; a.u = ((unsigned)h) << 16;
  return a.f;
}

#define GLOAD_LDS16(gp, lp)                                                   \
  __builtin_amdgcn_global_load_lds(                                           \
      (const __attribute__((address_space(1))) void*)(gp),                    \
      (__attribute__((address_space(3))) void*)(lp), 16, 0, 0)

// raw barrier + compiler memory fence (no vmcnt/lgkm drain inserted)
#define BAR()                                   \
  do {                                          \
    asm volatile("" ::: "memory");              \
    __builtin_amdgcn_s_barrier();               \
    asm volatile("" ::: "memory");              \
  } while (0)

// ---------------------------------------------------------------- router ---
__global__ __launch_bounds__(256) void router_kernel(
    const float* __restrict__ x, const float* __restrict__ Wg,
    int2* __restrict__ topi, float2* __restrict__ topv,
    float* __restrict__ blkimp) {
  __shared__ float wg[NE * DDIM];
  __shared__ float gsh[4][NE];
  int tid = threadIdx.x;
  for (int i = tid; i < NE * DDIM / 4; i += 256)
    ((float4*)wg)[i] = ((const float4*)Wg)[i];
  __syncthreads();
  int w = tid >> 6, lane = tid & 63;
  int t = blockIdx.x * 4 + w;
  const float* xr = x + (size_t)t * DDIM;
  float p[NE] = {0.f, 0.f, 0.f, 0.f, 0.f, 0.f, 0.f, 0.f};
#pragma unroll
  for (int j = 0; j < 16; ++j) {
    float xv = xr[lane + 64 * j];
#pragma unroll
    for (int e = 0; e < NE; ++e)
      p[e] = fmaf(xv, wg[e * DDIM + lane + 64 * j], p[e]);
  }
#pragma unroll
  for (int e = 0; e < NE; ++e) {
#pragma unroll
    for (int off = 32; off > 0; off >>= 1) p[e] += __shfl_xor(p[e], off, 64);
  }
  float mx = p[0];
#pragma unroll
  for (int e = 1; e < NE; ++e) mx = fmaxf(mx, p[e]);
  float g[NE];
  float s = 0.f;
#pragma unroll
  for (int e = 0; e < NE; ++e) { g[e] = expf(p[e] - mx); s += g[e]; }
  float inv = 1.0f / s;
#pragma unroll
  for (int e = 0; e < NE; ++e) g[e] *= inv;
  int i0 = 0; float v0 = g[0];
#pragma unroll
  for (int e = 1; e < NE; ++e) if (g[e] > v0) { v0 = g[e]; i0 = e; }
  int i1 = -1; float v1 = -1.0f;
#pragma unroll
  for (int e = 0; e < NE; ++e)
    if (e != i0 && g[e] > v1) { v1 = g[e]; i1 = e; }
  if (lane == 0) {
    topi[t] = make_int2(i0, i1);
    topv[t] = make_float2(v0, v1);
#pragma unroll
    for (int e = 0; e < NE; ++e) gsh[w][e] = g[e];
  }
  __syncthreads();
  if (tid < NE)
    blkimp[blockIdx.x * NE + tid] =
        gsh[0][tid] + gsh[1][tid] + gsh[2][tid] + gsh[3][tid];
}

// ---------------------------------------------- FCFS dispatch + losses -----
__global__ __launch_bounds__(256) void dispatch_kernel(
    const int2* __restrict__ topi, const float2* __restrict__ topv,
    const float* __restrict__ blkimp, int2* __restrict__ posmj,
    float2* __restrict__ wmaj, float* __restrict__ tail) {
  __shared__ unsigned char eid[2 * T_TOK];
  __shared__ unsigned short possm[2 * T_TOK];
  __shared__ int cnt_sh[NE];
  __shared__ float part[32][NE];
  int tid = threadIdx.x;
  for (int i = tid; i < T_TOK; i += 256) {
    int2 ti = topi[i];
    eid[i] = (unsigned char)ti.x;
    eid[T_TOK + i] = (unsigned char)ti.y;
  }
  __syncthreads();
  if (tid < 64) {
    int lane = tid;
    unsigned long long low = (1ull << lane) - 1ull;
    int c0 = 0, c1 = 0, c2 = 0, c3 = 0, c4 = 0, c5 = 0, c6 = 0, c7 = 0;
    for (int base = 0; base < 2 * T_TOK; base += 64) {
      int e = eid[base + lane];
      unsigned long long m0 = __ballot(e == 0);
      unsigned long long m1 = __ballot(e == 1);
      unsigned long long m2 = __ballot(e == 2);
      unsigned long long m3 = __ballot(e == 3);
      unsigned long long m4 = __ballot(e == 4);
      unsigned long long m5 = __ballot(e == 5);
      unsigned long long m6 = __ballot(e == 6);
      unsigned long long m7 = __ballot(e == 7);
      int rank = 0;
      if (e == 0) rank = c0 + __popcll(m0 & low);
      if (e == 1) rank = c1 + __popcll(m1 & low);
      if (e == 2) rank = c2 + __popcll(m2 & low);
      if (e == 3) rank = c3 + __popcll(m3 & low);
      if (e == 4) rank = c4 + __popcll(m4 & low);
      if (e == 5) rank = c5 + __popcll(m5 & low);
      if (e == 6) rank = c6 + __popcll(m6 & low);
      if (e == 7) rank = c7 + __popcll(m7 & low);
      possm[base + lane] = (unsigned short)((rank < CCAP) ? rank : CCAP);
      c0 += __popcll(m0); c1 += __popcll(m1); c2 += __popcll(m2);
      c3 += __popcll(m3); c4 += __popcll(m4); c5 += __popcll(m5);
      c6 += __popcll(m6); c7 += __popcll(m7);
    }
    if (lane == 0) {
      cnt_sh[0] = c0; cnt_sh[1] = c1; cnt_sh[2] = c2; cnt_sh[3] = c3;
      cnt_sh[4] = c4; cnt_sh[5] = c5; cnt_sh[6] = c6; cnt_sh[7] = c7;
    }
  }
  __syncthreads();
  for (int t = tid; t < T_TOK; t += 256) {
    int p0 = possm[t], p1 = possm[T_TOK + t];
    float2 tv = topv[t];
    float w0 = (p0 < CCAP) ? tv.x : 0.0f;
    float w1 = (p1 < CCAP) ? tv.y : 0.0f;
    float s = w0 + w1;
    if (s > 0.0f) { w0 /= s; w1 /= s; }
    posmj[t] = make_int2(p0, p1);
    wmaj[t] = make_float2(w0, w1);
  }
  {
    int sl = tid >> 3, e8 = tid & 7;
    float s = 0.f;
    for (int b = sl; b < 2048; b += 32) s += blkimp[b * NE + e8];
    part[sl][e8] = s;
  }
  __syncthreads();
  if (tid == 0) {
    float imp[NE], te[NE];
    for (int e = 0; e < NE; ++e) {
      float s = 0.f;
      for (int j = 0; j < 32; ++j) s += part[j][e];
      imp[e] = s;
      int c = cnt_sh[e];
      te[e] = (float)(c < CCAP ? c : CCAP);
    }
    float mi = 0.f, mt = 0.f;
    for (int e = 0; e < NE; ++e) { mi += imp[e]; mt += te[e]; }
    mi *= 0.125f; mt *= 0.125f;
    float vi = 0.f, vt = 0.f;
    for (int e = 0; e < NE; ++e) {
      vi += (imp[e] - mi) * (imp[e] - mi);
      vt += (te[e] - mt) * (te[e] - mt);
    }
    vi *= 0.125f; vt *= 0.125f;
    float ai = sqrtf(vi) / (mi + 1e-6f);
    float at = sqrtf(vt) / (mt + 1e-6f);
    tail[0] = 0.5f * (ai * ai + at * at);
    tail[1] = at * at;
  }
}

// --------------------------------------------------------------- scatter ---
__global__ __launch_bounds__(256) void scatter_kernel(
    const float* __restrict__ x, const int2* __restrict__ topi,
    const int2* __restrict__ posmj, unsigned short* __restrict__ ein) {
  int tid = threadIdx.x;
  int gid = blockIdx.x * 4 + (tid >> 6);
  int lane = tid & 63;
  int t = gid >> 1, k = gid & 1;
  int2 pp = posmj[t];
  int p = k ? pp.y : pp.x;
  if (p >= CCAP) return;
  int2 ii = topi[t];
  int e = k ? ii.y : ii.x;
  const float4* src = (const float4*)(x + (size_t)t * DDIM);
  unsigned short* dst = ein + ((size_t)e * CPAD + p) * DDIM;
#pragma unroll
  for (int j = 0; j < 4; ++j) {
    int c = j * 64 + lane;
    float4 v = src[c];
    ushort4v o;
    o.x = f2bf(v.x); o.y = f2bf(v.y); o.z = f2bf(v.z); o.w = f2bf(v.w);
    *(ushort4v*)(dst + (size_t)c * 4) = o;
  }
}

// ------------------------------------------------- weight transpose+cvt ----
__global__ __launch_bounds__(256) void transpose_cvt_kernel(
    const float* __restrict__ W, unsigned short* __restrict__ WT, int R,
    int Cc) {
  __shared__ unsigned short tile[64][72];
  int rt = R >> 6, ct = Cc >> 6;
  int per_e = rt * ct;
  int e = blockIdx.x / per_e;
  int rem = blockIdx.x % per_e;
  int tr = rem % rt, tc = rem / rt;
  int r0 = tr << 6, c0 = tc << 6;
  const float* We = W + (size_t)e * R * Cc;
  unsigned short* WTe = WT + (size_t)e * R * Cc;
  int tid = threadIdx.x;
  {
    int rl = tid >> 2, cb = (tid & 3) << 4;
    const float* src = We + (size_t)(r0 + rl) * Cc + c0 + cb;
#pragma unroll
    for (int j = 0; j < 16; j += 4) {
      float4 v = *(const float4*)(src + j);
      tile[rl][cb + j + 0] = f2bf(v.x);
      tile[rl][cb + j + 1] = f2bf(v.y);
      tile[rl][cb + j + 2] = f2bf(v.z);
      tile[rl][cb + j + 3] = f2bf(v.w);
    }
  }
  __syncthreads();
  {
    int cl = tid >> 2, rb = (tid & 3) << 4;
    unsigned short* dst = WTe + (size_t)(c0 + cl) * R + r0 + rb;
#pragma unroll
    for (int j = 0; j < 16; j += 4) {
      ushort4v o;
      o.x = tile[rb + j + 0][cl];
      o.y = tile[rb + j + 1][cl];
      o.z = tile[rb + j + 2][cl];
      o.w = tile[rb + j + 3][cl];
      *(ushort4v*)(dst + j) = o;
    }
  }
}

// ------------------------------------------------ 256x256 8-phase GEMM -----
// A: (E, M, Kz) bf16 row-major; B: (E, N, Kz) bf16 (B^T, K contiguous).
// Out: (E, M, N) bf16. 8 waves (2M x 4N), BK=64 split into 2 K-halves of 32.
// LDS: fragment-major subtiles (1024B per 16-row x 32-col), wave-linear reads
// (zero bank conflicts); global_load_lds with pre-permuted source addresses.
// Counted vmcnt(4) once per K-tile; raw s_barriers; setprio around MFMA.
template <bool GELU>
__global__ __launch_bounds__(512, 2) void gemm256_kernel(
    const unsigned short* __restrict__ A, const unsigned short* __restrict__ B,
    const float* __restrict__ bias, unsigned short* __restrict__ Out0,
    unsigned short* __restrict__ Out1, int M, int N, int Kz, int Ksub, int NT,
    int mt, int nt) {
  __shared__ __align__(16) char smem[131072];
  int nwg = gridDim.x;
  int bid = blockIdx.x;
  int swz = (bid & 7) * (nwg >> 3) + (bid >> 3);  // XCD-aware (nwg % 8 == 0)
  int bm = swz % mt;
  int r = swz / mt;
  int bn = r % nt;
  int r2 = r / nt;
  int e = r2 & 7;
  int ks = r2 >> 3;
  unsigned short* Outp = ks ? Out1 : Out0;
  int koff = ks * Ksub;

  int tid = threadIdx.x;
  int w = tid >> 6, lane = tid & 63;
  int wm = w >> 2, wn = w & 3;
  int fr = lane & 15, g = lane >> 4;
  size_t Kzs = (size_t)Kz;
  const unsigned short* Ae = A + ((size_t)e * M + (size_t)bm * 256) * Kzs + koff;
  const unsigned short* Be = B + ((size_t)e * N + (size_t)bn * 256) * Kzs + koff;

  // stage one half-tile (16KB): 2 x global_load_lds(16B) per thread.
  // LDS region: [isB(64KB)][buf(32KB)][kh(16KB)][m16(1KB)]; within a 1KB
  // subtile, layout is [g(256B)][fr(16B)] == lane*16 (fragment-major).
  auto stage = [&](const unsigned short* gb, int buf, int isB, int kh) {
#pragma unroll
    for (int j = 0; j < 2; ++j) {
      const unsigned short* src =
          gb + (size_t)((j * 8 + w) * 16 + fr) * Kzs + kh * 32 + g * 8;
      char* dst = smem + (isB << 16) + (buf << 15) + (kh << 14) +
                  ((j * 8 + w) << 10) + lane * 16;
      GLOAD_LDS16(src, dst);
    }
  };
  auto lda = [&](int buf, int kk, int m16) -> short8v {
    return *(const short8v*)(smem + (buf << 15) + (kk << 14) + (m16 << 10) +
                             lane * 16);
  };
  auto ldb = [&](int buf, int kk, int n16) -> short8v {
    return *(const short8v*)(smem + 65536 + (buf << 15) + (kk << 14) +
                             (n16 << 10) + lane * 16);
  };

  f32x4 acc[8][4] = {};

  // prologue: tile0 fully, tile1 kh0 halves; keep 2 halves in flight.
  stage(Ae, 0, 0, 0); stage(Be, 0, 1, 0);
  stage(Ae, 0, 0, 1); stage(Be, 0, 1, 1);
  stage(Ae + 64, 1, 0, 0); stage(Be + 64, 1, 1, 0);
  asm volatile("s_waitcnt vmcnt(4)" ::: "memory");
  BAR();

  for (int t = 0; t < NT; ++t) {
    int c = t & 1;
    const unsigned short* An1 = Ae + (size_t)(t + 1) * 64;
    const unsigned short* Bn1 = Be + (size_t)(t + 1) * 64;
    const unsigned short* An2 = Ae + (size_t)(t + 2) * 64;
    const unsigned short* Bn2 = Be + (size_t)(t + 2) * 64;
    short8v Bk[4], Af[4];
    // ---- p0: kk0, rows 0-3 ----
#pragma unroll
    for (int n = 0; n < 4; ++n) Bk[n] = ldb(c, 0, wn * 4 + n);
#pragma unroll
    for (int m = 0; m < 4; ++m) Af[m] = lda(c, 0, wm * 8 + m);
    if (t + 1 < NT) stage(An1, c ^ 1, 0, 1);
    BAR();
    __builtin_amdgcn_s_setprio(1);
#pragma unroll
    for (int m = 0; m < 4; ++m)
#pragma unroll
      for (int n = 0; n < 4; ++n)
        acc[m][n] = __builtin_amdgcn_mfma_f32_16x16x32_bf16(Af[m], Bk[n],
                                                            acc[m][n], 0, 0, 0);
    __builtin_amdgcn_s_setprio(0);
    BAR();
    // ---- p1: kk0, rows 4-7 (B regs reused) ----
#pragma unroll
    for (int m = 0; m < 4; ++m) Af[m] = lda(c, 0, wm * 8 + 4 + m);
    if (t + 1 < NT) stage(Bn1, c ^ 1, 1, 1);
    BAR();
    __builtin_amdgcn_s_setprio(1);
#pragma unroll
    for (int m = 0; m < 4; ++m)
#pragma unroll
      for (int n = 0; n < 4; ++n)
        acc[4 + m][n] = __builtin_amdgcn_mfma_f32_16x16x32_bf16(
            Af[m], Bk[n], acc[4 + m][n], 0, 0, 0);
    __builtin_amdgcn_s_setprio(0);
    BAR();
    // ---- p2: kk1, rows 0-3 ----
#pragma unroll
    for (int n = 0; n < 4; ++n) Bk[n] = ldb(c, 1, wn * 4 + n);
#pragma unroll
    for (int m = 0; m < 4; ++m) Af[m] = lda(c, 1, wm * 8 + m);
    if (t + 2 < NT) stage(An2, c, 0, 0);
    BAR();
    __builtin_amdgcn_s_setprio(1);
#pragma unroll
    for (int m = 0; m < 4; ++m)
#pragma unroll
      for (int n = 0; n < 4; ++n)
        acc[m][n] = __builtin_amdgcn_mfma_f32_16x16x32_bf16(Af[m], Bk[n],
                                                            acc[m][n], 0, 0, 0);
    __builtin_amdgcn_s_setprio(0);
    BAR();
    // ---- p3: kk1, rows 4-7 ; tile-boundary counted vmcnt ----
#pragma unroll
    for (int m = 0; m < 4; ++m) Af[m] = lda(c, 1, wm * 8 + 4 + m);
    if (t + 2 < NT) {
      stage(Bn2, c, 1, 0);
      asm volatile("s_waitcnt vmcnt(4)" ::: "memory");
    } else {
      asm volatile("s_waitcnt vmcnt(0)" ::: "memory");
    }
    BAR();
    __builtin_amdgcn_s_setprio(1);
#pragma unroll
    for (int m = 0; m < 4; ++m)
#pragma unroll
      for (int n = 0; n < 4; ++n)
        acc[4 + m][n] = __builtin_amdgcn_mfma_f32_16x16x32_bf16(
            Af[m], Bk[n], acc[4 + m][n], 0, 0, 0);
    __builtin_amdgcn_s_setprio(0);
    BAR();
  }

  // ---- epilogue: bias/GELU -> per-wave LDS bounce -> coalesced stores ----
  float bv[4];
#pragma unroll
  for (int n = 0; n < 4; ++n)
    bv[n] = (ks == 0)
                ? bias[(size_t)e * N + (size_t)bn * 256 + wn * 64 + n * 16 + fr]
                : 0.0f;
  char* wreg = smem + w * 16384;  // [128 rows][64 cols] u16, row stride 128B
#pragma unroll
  for (int m = 0; m < 8; ++m)
#pragma unroll
    for (int n = 0; n < 4; ++n)
#pragma unroll
      for (int j = 0; j < 4; ++j) {
        float v = acc[m][n][j] + bv[n];
        if (GELU) v = 0.5f * v * (1.0f + erff(v * 0.70710678118654752f));
        int rl = m * 16 + g * 4 + j;
        *(unsigned short*)(wreg + rl * 128 + (n * 16 + fr) * 2) = f2bf(v);
      }
  unsigned short* Oe = Outp +
                       ((size_t)e * M + (size_t)bm * 256 + (size_t)wm * 128) * N +
                       (size_t)bn * 256 + (size_t)wn * 64;
#pragma unroll
  for (int pass = 0; pass < 16; ++pass) {
    int rr = pass * 8 + (lane >> 3);
    int ch = lane & 7;
    short8v vv = *(const short8v*)(wreg + rr * 128 + ch * 16);
    *(short8v*)(Oe + (size_t)rr * N + ch * 8) = vv;
  }
}

// ---------------------------------------------------------------- gather ---
__global__ __launch_bounds__(256) void gather_kernel(
    const unsigned short* __restrict__ obufA,
    const unsigned short* __restrict__ obufB, const int2* __restrict__ topi,
    const int2* __restrict__ posmj, const float2* __restrict__ wmaj,
    float* __restrict__ y) {
  int tid = threadIdx.x;
  int w = tid >> 6, lane = tid & 63;
  int t = blockIdx.x * 4 + w;
  int2 pp = posmj[t];
  int2 ii = topi[t];
  float2 ww = wmaj[t];
  float* yr = y + (size_t)t * DDIM;
  size_t o0 = ((size_t)ii.x * CPAD + pp.x) * DDIM;
  size_t o1 = ((size_t)ii.y * CPAD + pp.y) * DDIM;
  bool v0 = pp.x < CCAP, v1 = pp.y < CCAP;
#pragma unroll
  for (int j = 0; j < 4; ++j) {
    int c = j * 64 + lane;
    float ax = 0.f, ay = 0.f, az = 0.f, aw = 0.f;
    if (v0) {
      ushort4v a = *(const ushort4v*)(obufA + o0 + (size_t)c * 4);
      ushort4v b = *(const ushort4v*)(obufB + o0 + (size_t)c * 4);
      ax += ww.x * (bf2f(a.x) + bf2f(b.x));
      ay += ww.x * (bf2f(a.y) + bf2f(b.y));
      az += ww.x * (bf2f(a.z) + bf2f(b.z));
      aw += ww.x * (bf2f(a.w) + bf2f(b.w));
    }
    if (v1) {
      ushort4v a = *(const ushort4v*)(obufA + o1 + (size_t)c * 4);
      ushort4v b = *(const ushort4v*)(obufB + o1 + (size_t)c * 4);
      ax += ww.y * (bf2f(a.x) + bf2f(b.x));
      ay += ww.y * (bf2f(a.y) + bf2f(b.y));
      az += ww.y * (bf2f(a.z) + bf2f(b.z));
      aw += ww.y * (bf2f(a.w) + bf2f(b.w));
    }
    ((float4*)yr)[c] = make_float4(ax, ay, az, aw);
  }
}

// ---------------------------------------------------------------------------
extern "C" void kernel_launch(void* const* d_in, const int* in_sizes, int n_in,
                              void* d_out, int out_size, void* d_ws,
                              size_t ws_size, hipStream_t stream) {
  (void)in_sizes; (void)n_in; (void)out_size; (void)ws_size;
  const float* x = (const float*)d_in[0];
  const float* Wg = (const float*)d_in[1];
  const float* W1 = (const float*)d_in[2];
  const float* b1 = (const float*)d_in[3];
  const float* W2 = (const float*)d_in[4];
  const float* b2 = (const float*)d_in[5];
  float* out = (float*)d_out;

  char* ws = (char*)d_ws;
  size_t off = 0;
  auto alloc = [&](size_t b) {
    char* p = ws + off;
    off += (b + 255) & ~(size_t)255;
    return p;
  };
  unsigned short* ein = (unsigned short*)alloc((size_t)NE * CPAD * DDIM * 2);
  unsigned short* hbuf = (unsigned short*)alloc((size_t)NE * CPAD * HDIM * 2);
  unsigned short* obuf = (unsigned short*)alloc((size_t)NE * CPAD * DDIM * 2);
  unsigned short* w1t = (unsigned short*)alloc((size_t)NE * HDIM * DDIM * 2);
  unsigned short* w2t = (unsigned short*)alloc((size_t)NE * DDIM * HDIM * 2);
  int2* topi = (int2*)alloc(T_TOK * sizeof(int2));
  float2* topv = (float2*)alloc(T_TOK * sizeof(float2));
  int2* posmj = (int2*)alloc(T_TOK * sizeof(int2));
  float2* wmaj = (float2*)alloc(T_TOK * sizeof(float2));
  float* blkimp = (float*)alloc(2048 * NE * sizeof(float));

  transpose_cvt_kernel<<<NE * (DDIM / 64) * (HDIM / 64), 256, 0, stream>>>(
      W1, w1t, DDIM, HDIM);
  transpose_cvt_kernel<<<NE * (HDIM / 64) * (DDIM / 64), 256, 0, stream>>>(
      W2, w2t, HDIM, DDIM);
  router_kernel<<<T_TOK / 4, 256, 0, stream>>>(x, Wg, topi, topv, blkimp);
  dispatch_kernel<<<1, 256, 0, stream>>>(topi, topv, blkimp, posmj, wmaj,
                                         out + (size_t)T_TOK * DDIM);
  scatter_kernel<<<(2 * T_TOK) / 4, 256, 0, stream>>>(x, topi, posmj, ein);

  // gemm1: (E,2304,1024) x (E,4096,1024)^T -> hbuf (E,2304,4096), GELU+b1
  gemm256_kernel<true><<<NE * 9 * 16, 512, 0, stream>>>(
      ein, w1t, b1, hbuf, hbuf, CPAD, HDIM, DDIM, DDIM, DDIM / 64, 9, 16);
  // gemm2: (E,2304,4096) x (E,1024,4096)^T -> obuf (+b2) and ein (split-K)
  gemm256_kernel<false><<<NE * 9 * 4 * 2, 512, 0, stream>>>(
      hbuf, w2t, b2, obuf, ein, CPAD, DDIM, HDIM, HDIM / 2, HDIM / 128, 9, 4);

  gather_kernel<<<T_TOK / 4, 256, 0, stream>>>(obuf, ein, topi, posmj, wmaj,
                                               out);
}

// Round 3
// 680.863 us; speedup vs baseline: 1.2119x; 1.0035x over previous
//
#include <hip/hip_runtime.h>
#include <math.h>

typedef short short8v __attribute__((ext_vector_type(8)));
typedef float f32x4 __attribute__((ext_vector_type(4)));
typedef unsigned short ushort4v __attribute__((ext_vector_type(4)));

#define T_TOK 8192
#define DDIM 1024
#define HDIM 4096
#define NE 8
#define CCAP 2150
#define CPAD 2304   // 9 * 256

__device__ __forceinline__ unsigned short f2bf(float f) {
  union { float f; unsigned u; } a; a.f = f;
  unsigned r = a.u + 0x7fffu + ((a.u >> 16) & 1u);   // RNE
  return (unsigned short)(r >> 16);
}
__device__ __forceinline__ float bf2f(unsigned short h) {
  union { unsigned u; float f; } a; a.u = ((unsigned)h) << 16;
  return a.f;
}

#define GLOAD_LDS16(gp, lp)                                                   \
  __builtin_amdgcn_global_load_lds(                                           \
      (const __attribute__((address_space(1))) void*)(gp),                    \
      (__attribute__((address_space(3))) void*)(lp), 16, 0, 0)

// raw barrier (no implicit vmcnt/lgkm drain)
#define BAR()                                   \
  do {                                          \
    asm volatile("" ::: "memory");              \
    __builtin_amdgcn_s_barrier();               \
    asm volatile("" ::: "memory");              \
  } while (0)

// ---------------------------------------------------------------- router ---
__global__ __launch_bounds__(256) void router_kernel(
    const float* __restrict__ x, const float* __restrict__ Wg,
    int2* __restrict__ topi, float2* __restrict__ topv,
    float* __restrict__ blkimp) {
  __shared__ float wg[NE * DDIM];
  __shared__ float gsh[4][NE];
  int tid = threadIdx.x;
  for (int i = tid; i < NE * DDIM / 4; i += 256)
    ((float4*)wg)[i] = ((const float4*)Wg)[i];
  __syncthreads();
  int w = tid >> 6, lane = tid & 63;
  int t = blockIdx.x * 4 + w;
  const float* xr = x + (size_t)t * DDIM;
  float p[NE] = {0.f, 0.f, 0.f, 0.f, 0.f, 0.f, 0.f, 0.f};
#pragma unroll
  for (int j = 0; j < 16; ++j) {
    float xv = xr[lane + 64 * j];
#pragma unroll
    for (int e = 0; e < NE; ++e)
      p[e] = fmaf(xv, wg[e * DDIM + lane + 64 * j], p[e]);
  }
#pragma unroll
  for (int e = 0; e < NE; ++e) {
#pragma unroll
    for (int off = 32; off > 0; off >>= 1) p[e] += __shfl_xor(p[e], off, 64);
  }
  float mx = p[0];
#pragma unroll
  for (int e = 1; e < NE; ++e) mx = fmaxf(mx, p[e]);
  float g[NE];
  float s = 0.f;
#pragma unroll
  for (int e = 0; e < NE; ++e) { g[e] = expf(p[e] - mx); s += g[e]; }
  float inv = 1.0f / s;
#pragma unroll
  for (int e = 0; e < NE; ++e) g[e] *= inv;
  int i0 = 0; float v0 = g[0];
#pragma unroll
  for (int e = 1; e < NE; ++e) if (g[e] > v0) { v0 = g[e]; i0 = e; }
  int i1 = -1; float v1 = -1.0f;
#pragma unroll
  for (int e = 0; e < NE; ++e)
    if (e != i0 && g[e] > v1) { v1 = g[e]; i1 = e; }
  if (lane == 0) {
    topi[t] = make_int2(i0, i1);
    topv[t] = make_float2(v0, v1);
#pragma unroll
    for (int e = 0; e < NE; ++e) gsh[w][e] = g[e];
  }
  __syncthreads();
  if (tid < NE)
    blkimp[blockIdx.x * NE + tid] =
        gsh[0][tid] + gsh[1][tid] + gsh[2][tid] + gsh[3][tid];
}

// ---------------------------------------------- FCFS dispatch + losses -----
__global__ __launch_bounds__(256) void dispatch_kernel(
    const int2* __restrict__ topi, const float2* __restrict__ topv,
    const float* __restrict__ blkimp, int2* __restrict__ posmj,
    float2* __restrict__ wmaj, float* __restrict__ tail) {
  __shared__ unsigned char eid[2 * T_TOK];
  __shared__ unsigned short possm[2 * T_TOK];
  __shared__ int cnt_sh[NE];
  __shared__ float part[32][NE];
  int tid = threadIdx.x;
  for (int i = tid; i < T_TOK; i += 256) {
    int2 ti = topi[i];
    eid[i] = (unsigned char)ti.x;
    eid[T_TOK + i] = (unsigned char)ti.y;
  }
  __syncthreads();
  if (tid < 64) {
    int lane = tid;
    unsigned long long low = (1ull << lane) - 1ull;
    int c0 = 0, c1 = 0, c2 = 0, c3 = 0, c4 = 0, c5 = 0, c6 = 0, c7 = 0;
    for (int base = 0; base < 2 * T_TOK; base += 64) {
      int e = eid[base + lane];
      unsigned long long m0 = __ballot(e == 0);
      unsigned long long m1 = __ballot(e == 1);
      unsigned long long m2 = __ballot(e == 2);
      unsigned long long m3 = __ballot(e == 3);
      unsigned long long m4 = __ballot(e == 4);
      unsigned long long m5 = __ballot(e == 5);
      unsigned long long m6 = __ballot(e == 6);
      unsigned long long m7 = __ballot(e == 7);
      int rank = 0;
      if (e == 0) rank = c0 + __popcll(m0 & low);
      if (e == 1) rank = c1 + __popcll(m1 & low);
      if (e == 2) rank = c2 + __popcll(m2 & low);
      if (e == 3) rank = c3 + __popcll(m3 & low);
      if (e == 4) rank = c4 + __popcll(m4 & low);
      if (e == 5) rank = c5 + __popcll(m5 & low);
      if (e == 6) rank = c6 + __popcll(m6 & low);
      if (e == 7) rank = c7 + __popcll(m7 & low);
      possm[base + lane] = (unsigned short)((rank < CCAP) ? rank : CCAP);
      c0 += __popcll(m0); c1 += __popcll(m1); c2 += __popcll(m2);
      c3 += __popcll(m3); c4 += __popcll(m4); c5 += __popcll(m5);
      c6 += __popcll(m6); c7 += __popcll(m7);
    }
    if (lane == 0) {
      cnt_sh[0] = c0; cnt_sh[1] = c1; cnt_sh[2] = c2; cnt_sh[3] = c3;
      cnt_sh[4] = c4; cnt_sh[5] = c5; cnt_sh[6] = c6; cnt_sh[7] = c7;
    }
  }
  __syncthreads();
  for (int t = tid; t < T_TOK; t += 256) {
    int p0 = possm[t], p1 = possm[T_TOK + t];
    float2 tv = topv[t];
    float w0 = (p0 < CCAP) ? tv.x : 0.0f;
    float w1 = (p1 < CCAP) ? tv.y : 0.0f;
    float s = w0 + w1;
    if (s > 0.0f) { w0 /= s; w1 /= s; }
    posmj[t] = make_int2(p0, p1);
    wmaj[t] = make_float2(w0, w1);
  }
  {
    int sl = tid >> 3, e8 = tid & 7;
    float s = 0.f;
    for (int b = sl; b < 2048; b += 32) s += blkimp[b * NE + e8];
    part[sl][e8] = s;
  }
  __syncthreads();
  if (tid == 0) {
    float imp[NE], te[NE];
    for (int e = 0; e < NE; ++e) {
      float s = 0.f;
      for (int j = 0; j < 32; ++j) s += part[j][e];
      imp[e] = s;
      int c = cnt_sh[e];
      te[e] = (float)(c < CCAP ? c : CCAP);
    }
    float mi = 0.f, mt = 0.f;
    for (int e = 0; e < NE; ++e) { mi += imp[e]; mt += te[e]; }
    mi *= 0.125f; mt *= 0.125f;
    float vi = 0.f, vt = 0.f;
    for (int e = 0; e < NE; ++e) {
      vi += (imp[e] - mi) * (imp[e] - mi);
      vt += (te[e] - mt) * (te[e] - mt);
    }
    vi *= 0.125f; vt *= 0.125f;
    float ai = sqrtf(vi) / (mi + 1e-6f);
    float at = sqrtf(vt) / (mt + 1e-6f);
    tail[0] = 0.5f * (ai * ai + at * at);
    tail[1] = at * at;
  }
}

// --------------------------------------------------------------- scatter ---
__global__ __launch_bounds__(256) void scatter_kernel(
    const float* __restrict__ x, const int2* __restrict__ topi,
    const int2* __restrict__ posmj, unsigned short* __restrict__ ein) {
  int tid = threadIdx.x;
  int gid = blockIdx.x * 4 + (tid >> 6);
  int lane = tid & 63;
  int t = gid >> 1, k = gid & 1;
  int2 pp = posmj[t];
  int p = k ? pp.y : pp.x;
  if (p >= CCAP) return;
  int2 ii = topi[t];
  int e = k ? ii.y : ii.x;
  const float4* src = (const float4*)(x + (size_t)t * DDIM);
  unsigned short* dst = ein + ((size_t)e * CPAD + p) * DDIM;
#pragma unroll
  for (int j = 0; j < 4; ++j) {
    int c = j * 64 + lane;
    float4 v = src[c];
    ushort4v o;
    o.x = f2bf(v.x); o.y = f2bf(v.y); o.z = f2bf(v.z); o.w = f2bf(v.w);
    *(ushort4v*)(dst + (size_t)c * 4) = o;
  }
}

// ------------------------------------------------- weight transpose+cvt ----
__global__ __launch_bounds__(256) void transpose_cvt_kernel(
    const float* __restrict__ W, unsigned short* __restrict__ WT, int R,
    int Cc) {
  __shared__ unsigned short tile[64][72];
  int rt = R >> 6, ct = Cc >> 6;
  int per_e = rt * ct;
  int e = blockIdx.x / per_e;
  int rem = blockIdx.x % per_e;
  int tr = rem % rt, tc = rem / rt;
  int r0 = tr << 6, c0 = tc << 6;
  const float* We = W + (size_t)e * R * Cc;
  unsigned short* WTe = WT + (size_t)e * R * Cc;
  int tid = threadIdx.x;
  {
    int rl = tid >> 2, cb = (tid & 3) << 4;
    const float* src = We + (size_t)(r0 + rl) * Cc + c0 + cb;
#pragma unroll
    for (int j = 0; j < 16; j += 4) {
      float4 v = *(const float4*)(src + j);
      tile[rl][cb + j + 0] = f2bf(v.x);
      tile[rl][cb + j + 1] = f2bf(v.y);
      tile[rl][cb + j + 2] = f2bf(v.z);
      tile[rl][cb + j + 3] = f2bf(v.w);
    }
  }
  __syncthreads();
  {
    int cl = tid >> 2, rb = (tid & 3) << 4;
    unsigned short* dst = WTe + (size_t)(c0 + cl) * R + r0 + rb;
#pragma unroll
    for (int j = 0; j < 16; j += 4) {
      ushort4v o;
      o.x = tile[rb + j + 0][cl];
      o.y = tile[rb + j + 1][cl];
      o.z = tile[rb + j + 2][cl];
      o.w = tile[rb + j + 3][cl];
      *(ushort4v*)(dst + j) = o;
    }
  }
}

// ------------------------------------------------ 256x256 pipelined GEMM ---
// A: (E, M, Kz) bf16 row-major; B: (E, N, Kz) bf16 (B^T, K contiguous).
// Out (E,M,N) bf16. 8 waves (2Mx4N), BK=64 (2 kk of 32), 4 phases/K-tile.
// Software-pipelined: phase p issues phase p+1's ds_reads before p's MFMA
// (compiler emits counted lgkmcnt -> no post-barrier LDS stall). Deep vmem:
// W1=vmcnt(6) at p0-end, W3=vmcnt(8) at p3 -- each retires loads issued a
// full K-tile earlier. Reads of freshly staged LDS only after [wait; BAR]
// (per-wave vmcnt only confirms own portion; barrier makes it collective).
template <bool GELU>
__global__ __launch_bounds__(512, 2) void gemm256_kernel(
    const unsigned short* __restrict__ A, const unsigned short* __restrict__ B,
    const float* __restrict__ bias, unsigned short* __restrict__ Out0,
    unsigned short* __restrict__ Out1, int M, int N, int Kz, int Ksub, int NT,
    int mt, int nt) {
  __shared__ __align__(16) char smem[131072];
  int nwg = gridDim.x;
  int bid = blockIdx.x;
  int swz = (bid & 7) * (nwg >> 3) + (bid >> 3);  // XCD-aware (nwg % 8 == 0)
  int bm = swz % mt;
  int r = swz / mt;
  int bn = r % nt;
  int r2 = r / nt;
  int e = r2 & 7;
  int ks = r2 >> 3;
  unsigned short* Outp = ks ? Out1 : Out0;
  int koff = ks * Ksub;

  int tid = threadIdx.x;
  int w = tid >> 6, lane = tid & 63;
  int wm = w >> 2, wn = w & 3;
  int fr = lane & 15, g = lane >> 4;
  size_t Kzs = (size_t)Kz;
  const char* Ab = (const char*)(A + ((size_t)e * M + (size_t)bm * 256) * Kzs + koff);
  const char* Bb = (const char*)(B + ((size_t)e * N + (size_t)bn * 256) * Kzs + koff);

  // per-thread global row offsets (bytes) for staging; LDS dests are linear.
  size_t ro0 = (size_t)(w * 16 + fr) * Kzs * 2 + (size_t)g * 16;
  size_t ro1 = ro0 + (size_t)128 * Kzs * 2;
  int ld0 = (w << 10) + lane * 16;
  int ld1 = ((8 + w) << 10) + lane * 16;

  // stage one 16KB half: [isB(64KB)][buf(32KB)][kh(16KB)][row16(1KB)][lane*16]
  auto stage = [&](const char* gb, int buf, int isB, int kh) {
    int base = (isB << 16) + (buf << 15) + (kh << 14);
    GLOAD_LDS16(gb + ro0 + kh * 64, smem + base + ld0);
    GLOAD_LDS16(gb + ro1 + kh * 64, smem + base + ld1);
  };
  auto lda = [&](int buf, int kk, int m16) -> short8v {
    return *(const short8v*)(smem + (buf << 15) + (kk << 14) + (m16 << 10) +
                             lane * 16);
  };
  auto ldb = [&](int buf, int kk, int n16) -> short8v {
    return *(const short8v*)(smem + 65536 + (buf << 15) + (kk << 14) +
                             (n16 << 10) + lane * 16);
  };

  f32x4 acc[8][4] = {};
  short8v a0[4], a1[4], b0[4], b1[4];

  // prologue: t0 full (kh0,kh1), t1 kh0 -- in age order for the vmcnt ledger.
  stage(Ab, 0, 0, 0); stage(Bb, 0, 1, 0);
  stage(Ab, 0, 0, 1); stage(Bb, 0, 1, 1);
  stage(Ab + 128, 1, 0, 0); stage(Bb + 128, 1, 1, 0);
  asm volatile("s_waitcnt vmcnt(8)" ::: "memory");  // t0 kh0 landed (own part)
  BAR();                                            // collective confirm
#pragma unroll
  for (int m = 0; m < 4; ++m) a0[m] = lda(0, 0, wm * 8 + m);
#pragma unroll
  for (int n = 0; n < 4; ++n) b0[n] = ldb(0, 0, wn * 4 + n);

  for (int t = 0; t < NT; ++t) {
    int c = t & 1, cn = c ^ 1;
    const char* At1 = Ab + (size_t)(t + 1) * 128;
    const char* Bt1 = Bb + (size_t)(t + 1) * 128;
    const char* At2 = Ab + (size_t)(t + 2) * 128;
    const char* Bt2 = Bb + (size_t)(t + 2) * 128;
    // ---- p0: MFMA rows0-3 kk0 (a0,b0); prefetch p1's A; stage A-kh1(t+1) --
#pragma unroll
    for (int m = 0; m < 4; ++m) a1[m] = lda(c, 0, wm * 8 + 4 + m);
    if (t + 1 < NT) stage(At1, cn, 0, 1);
    BAR();
    __builtin_amdgcn_s_setprio(1);
#pragma unroll
    for (int m = 0; m < 4; ++m)
#pragma unroll
      for (int n = 0; n < 4; ++n)
        acc[m][n] = __builtin_amdgcn_mfma_f32_16x16x32_bf16(a0[m], b0[n],
                                                            acc[m][n], 0, 0, 0);
    __builtin_amdgcn_s_setprio(0);
    if (t + 1 < NT) {  // W1: retire kh1(t) staged at t-1 p0/p1
      asm volatile("s_waitcnt vmcnt(6)" ::: "memory");
    } else {
      asm volatile("s_waitcnt vmcnt(0)" ::: "memory");
    }
    BAR();  // collective confirm of kh1(t) before p1's kk1 reads
    // ---- p1: MFMA rows4-7 kk0 (a1,b0); prefetch p2 (kk1); stage B-kh1 -----
#pragma unroll
    for (int m = 0; m < 4; ++m) a0[m] = lda(c, 1, wm * 8 + m);
#pragma unroll
    for (int n = 0; n < 4; ++n) b1[n] = ldb(c, 1, wn * 4 + n);
    if (t + 1 < NT) stage(Bt1, cn, 1, 1);
    BAR();
    __builtin_amdgcn_s_setprio(1);
#pragma unroll
    for (int m = 0; m < 4; ++m)
#pragma unroll
      for (int n = 0; n < 4; ++n)
        acc[4 + m][n] = __builtin_amdgcn_mfma_f32_16x16x32_bf16(
            a1[m], b0[n], acc[4 + m][n], 0, 0, 0);
    __builtin_amdgcn_s_setprio(0);
    BAR();
    // ---- p2: MFMA rows0-3 kk1 (a0,b1); prefetch p3's A; stage A-kh0(t+2) --
#pragma unroll
    for (int m = 0; m < 4; ++m) a1[m] = lda(c, 1, wm * 8 + 4 + m);
    if (t + 2 < NT) stage(At2, c, 0, 0);
    BAR();
    __builtin_amdgcn_s_setprio(1);
#pragma unroll
    for (int m = 0; m < 4; ++m)
#pragma unroll
      for (int n = 0; n < 4; ++n)
        acc[m][n] = __builtin_amdgcn_mfma_f32_16x16x32_bf16(a0[m], b1[n],
                                                            acc[m][n], 0, 0, 0);
    __builtin_amdgcn_s_setprio(0);
    BAR();
    // ---- p3: stage B-kh0(t+2); W3; BAR; cross-tile prefetch; MFMA ---------
    if (t + 2 < NT) {
      stage(Bt2, c, 1, 0);
      asm volatile("s_waitcnt vmcnt(8)" ::: "memory");  // retire kh0(t+1)
    } else if (t + 1 < NT) {
      asm volatile("s_waitcnt vmcnt(4)" ::: "memory");
    } else {
      asm volatile("s_waitcnt vmcnt(0)" ::: "memory");
    }
    BAR();  // collective confirm of kh0(t+1)
    if (t + 1 < NT) {
#pragma unroll
      for (int m = 0; m < 4; ++m) a0[m] = lda(cn, 0, wm * 8 + m);
#pragma unroll
      for (int n = 0; n < 4; ++n) b0[n] = ldb(cn, 0, wn * 4 + n);
    }
    __builtin_amdgcn_s_setprio(1);
#pragma unroll
    for (int m = 0; m < 4; ++m)
#pragma unroll
      for (int n = 0; n < 4; ++n)
        acc[4 + m][n] = __builtin_amdgcn_mfma_f32_16x16x32_bf16(
            a1[m], b1[n], acc[4 + m][n], 0, 0, 0);
    __builtin_amdgcn_s_setprio(0);
    BAR();
  }

  // ---- epilogue: bias/GELU -> per-wave LDS bounce -> coalesced stores ----
  float bv[4];
#pragma unroll
  for (int n = 0; n < 4; ++n)
    bv[n] = (ks == 0)
                ? bias[(size_t)e * N + (size_t)bn * 256 + wn * 64 + n * 16 + fr]
                : 0.0f;
  char* wreg = smem + w * 16384;  // [128 rows][64 cols] u16, row stride 128B
#pragma unroll
  for (int m = 0; m < 8; ++m)
#pragma unroll
    for (int n = 0; n < 4; ++n)
#pragma unroll
      for (int j = 0; j < 4; ++j) {
        float v = acc[m][n][j] + bv[n];
        if (GELU) v = 0.5f * v * (1.0f + erff(v * 0.70710678118654752f));
        int rl = m * 16 + g * 4 + j;
        *(unsigned short*)(wreg + rl * 128 + (n * 16 + fr) * 2) = f2bf(v);
      }
  unsigned short* Oe = Outp +
                       ((size_t)e * M + (size_t)bm * 256 + (size_t)wm * 128) * N +
                       (size_t)bn * 256 + (size_t)wn * 64;
#pragma unroll
  for (int pass = 0; pass < 16; ++pass) {
    int rr = pass * 8 + (lane >> 3);
    int ch = lane & 7;
    short8v vv = *(const short8v*)(wreg + rr * 128 + ch * 16);
    *(short8v*)(Oe + (size_t)rr * N + ch * 8) = vv;
  }
}

// ---------------------------------------------------------------- gather ---
__global__ __launch_bounds__(256) void gather_kernel(
    const unsigned short* __restrict__ obufA,
    const unsigned short* __restrict__ obufB, const int2* __restrict__ topi,
    const int2* __restrict__ posmj, const float2* __restrict__ wmaj,
    float* __restrict__ y) {
  int tid = threadIdx.x;
  int w = tid >> 6, lane = tid & 63;
  int t = blockIdx.x * 4 + w;
  int2 pp = posmj[t];
  int2 ii = topi[t];
  float2 ww = wmaj[t];
  float* yr = y + (size_t)t * DDIM;
  size_t o0 = ((size_t)ii.x * CPAD + pp.x) * DDIM;
  size_t o1 = ((size_t)ii.y * CPAD + pp.y) * DDIM;
  bool v0 = pp.x < CCAP, v1 = pp.y < CCAP;
#pragma unroll
  for (int j = 0; j < 4; ++j) {
    int c = j * 64 + lane;
    float ax = 0.f, ay = 0.f, az = 0.f, aw = 0.f;
    if (v0) {
      ushort4v a = *(const ushort4v*)(obufA + o0 + (size_t)c * 4);
      ushort4v b = *(const ushort4v*)(obufB + o0 + (size_t)c * 4);
      ax += ww.x * (bf2f(a.x) + bf2f(b.x));
      ay += ww.x * (bf2f(a.y) + bf2f(b.y));
      az += ww.x * (bf2f(a.z) + bf2f(b.z));
      aw += ww.x * (bf2f(a.w) + bf2f(b.w));
    }
    if (v1) {
      ushort4v a = *(const ushort4v*)(obufA + o1 + (size_t)c * 4);
      ushort4v b = *(const ushort4v*)(obufB + o1 + (size_t)c * 4);
      ax += ww.y * (bf2f(a.x) + bf2f(b.x));
      ay += ww.y * (bf2f(a.y) + bf2f(b.y));
      az += ww.y * (bf2f(a.z) + bf2f(b.z));
      aw += ww.y * (bf2f(a.w) + bf2f(b.w));
    }
    ((float4*)yr)[c] = make_float4(ax, ay, az, aw);
  }
}

// ---------------------------------------------------------------------------
extern "C" void kernel_launch(void* const* d_in, const int* in_sizes, int n_in,
                              void* d_out, int out_size, void* d_ws,
                              size_t ws_size, hipStream_t stream) {
  (void)in_sizes; (void)n_in; (void)out_size; (void)ws_size;
  const float* x = (const float*)d_in[0];
  const float* Wg = (const float*)d_in[1];
  const float* W1 = (const float*)d_in[2];
  const float* b1 = (const float*)d_in[3];
  const float* W2 = (const float*)d_in[4];
  const float* b2 = (const float*)d_in[5];
  float* out = (float*)d_out;

  char* ws = (char*)d_ws;
  size_t off = 0;
  auto alloc = [&](size_t b) {
    char* p = ws + off;
    off += (b + 255) & ~(size_t)255;
    return p;
  };
  unsigned short* ein = (unsigned short*)alloc((size_t)NE * CPAD * DDIM * 2);
  unsigned short* hbuf = (unsigned short*)alloc((size_t)NE * CPAD * HDIM * 2);
  unsigned short* obuf = (unsigned short*)alloc((size_t)NE * CPAD * DDIM * 2);
  unsigned short* w1t = (unsigned short*)alloc((size_t)NE * HDIM * DDIM * 2);
  unsigned short* w2t = (unsigned short*)alloc((size_t)NE * DDIM * HDIM * 2);
  int2* topi = (int2*)alloc(T_TOK * sizeof(int2));
  float2* topv = (float2*)alloc(T_TOK * sizeof(float2));
  int2* posmj = (int2*)alloc(T_TOK * sizeof(int2));
  float2* wmaj = (float2*)alloc(T_TOK * sizeof(float2));
  float* blkimp = (float*)alloc(2048 * NE * sizeof(float));

  transpose_cvt_kernel<<<NE * (DDIM / 64) * (HDIM / 64), 256, 0, stream>>>(
      W1, w1t, DDIM, HDIM);
  transpose_cvt_kernel<<<NE * (HDIM / 64) * (DDIM / 64), 256, 0, stream>>>(
      W2, w2t, HDIM, DDIM);
  router_kernel<<<T_TOK / 4, 256, 0, stream>>>(x, Wg, topi, topv, blkimp);
  dispatch_kernel<<<1, 256, 0, stream>>>(topi, topv, blkimp, posmj, wmaj,
                                         out + (size_t)T_TOK * DDIM);
  scatter_kernel<<<(2 * T_TOK) / 4, 256, 0, stream>>>(x, topi, posmj, ein);

  // gemm1: (E,2304,1024) x (E,4096,1024)^T -> hbuf (E,2304,4096), GELU+b1
  gemm256_kernel<true><<<NE * 9 * 16, 512, 0, stream>>>(
      ein, w1t, b1, hbuf, hbuf, CPAD, HDIM, DDIM, DDIM, DDIM / 64, 9, 16);
  // gemm2: (E,2304,4096) x (E,1024,4096)^T -> obuf (+b2) and ein (split-K)
  gemm256_kernel<false><<<NE * 9 * 4 * 2, 512, 0, stream>>>(
      hbuf, w2t, b2, obuf, ein, CPAD, DDIM, HDIM, HDIM / 2, HDIM / 128, 9, 4);

  gather_kernel<<<T_TOK / 4, 256, 0, stream>>>(obuf, ein, topi, posmj, wmaj,
                                               out);
}

// Round 4
// 677.355 us; speedup vs baseline: 1.2181x; 1.0052x over previous
//
#include <hip/hip_runtime.h>
#include <math.h>

typedef short short8v __attribute__((ext_vector_type(8)));
typedef float f32x4 __attribute__((ext_vector_type(4)));
typedef unsigned short ushort4v __attribute__((ext_vector_type(4)));

#define T_TOK 8192
#define DDIM 1024
#define HDIM 4096
#define NE 8
#define CCAP 2150
#define CPAD 2304   // 9 * 256

__device__ __forceinline__ unsigned short f2bf(float f) {
  union { float f; unsigned u; } a; a.f = f;
  unsigned r = a.u + 0x7fffu + ((a.u >> 16) & 1u);   // RNE
  return (unsigned short)(r >> 16);
}
__device__ __forceinline__ float bf2f(unsigned short h) {
  union { unsigned u; float f; } a; a.u = ((unsigned)h) << 16;
  return a.f;
}

#define GLOAD_LDS16(gp, lp)                                                   \
  __builtin_amdgcn_global_load_lds(                                           \
      (const __attribute__((address_space(1))) void*)(gp),                    \
      (__attribute__((address_space(3))) void*)(lp), 16, 0, 0)

// asm ds_read_b128: invisible to the compiler's waitcnt-insertion pass, so
// no auto vmcnt(0) is generated against global_load_lds LDS writes.
__device__ __forceinline__ short8v ds_read128(unsigned addr) {
  short8v v;
  asm volatile("ds_read_b128 %0, %1" : "=v"(v) : "v"(addr));
  return v;
}

#define BAR() __builtin_amdgcn_s_barrier()
#define WLGKM0()                                  \
  do {                                            \
    asm volatile("s_waitcnt lgkmcnt(0)");         \
    __builtin_amdgcn_sched_barrier(0);            \
  } while (0)

// ---------------------------------------------------------------- router ---
__global__ __launch_bounds__(256) void router_kernel(
    const float* __restrict__ x, const float* __restrict__ Wg,
    int2* __restrict__ topi, float2* __restrict__ topv,
    float* __restrict__ blkimp) {
  __shared__ float wg[NE * DDIM];
  __shared__ float gsh[4][NE];
  int tid = threadIdx.x;
  for (int i = tid; i < NE * DDIM / 4; i += 256)
    ((float4*)wg)[i] = ((const float4*)Wg)[i];
  __syncthreads();
  int w = tid >> 6, lane = tid & 63;
  int t = blockIdx.x * 4 + w;
  const float* xr = x + (size_t)t * DDIM;
  float p[NE] = {0.f, 0.f, 0.f, 0.f, 0.f, 0.f, 0.f, 0.f};
#pragma unroll
  for (int j = 0; j < 16; ++j) {
    float xv = xr[lane + 64 * j];
#pragma unroll
    for (int e = 0; e < NE; ++e)
      p[e] = fmaf(xv, wg[e * DDIM + lane + 64 * j], p[e]);
  }
#pragma unroll
  for (int e = 0; e < NE; ++e) {
#pragma unroll
    for (int off = 32; off > 0; off >>= 1) p[e] += __shfl_xor(p[e], off, 64);
  }
  float mx = p[0];
#pragma unroll
  for (int e = 1; e < NE; ++e) mx = fmaxf(mx, p[e]);
  float g[NE];
  float s = 0.f;
#pragma unroll
  for (int e = 0; e < NE; ++e) { g[e] = expf(p[e] - mx); s += g[e]; }
  float inv = 1.0f / s;
#pragma unroll
  for (int e = 0; e < NE; ++e) g[e] *= inv;
  int i0 = 0; float v0 = g[0];
#pragma unroll
  for (int e = 1; e < NE; ++e) if (g[e] > v0) { v0 = g[e]; i0 = e; }
  int i1 = -1; float v1 = -1.0f;
#pragma unroll
  for (int e = 0; e < NE; ++e)
    if (e != i0 && g[e] > v1) { v1 = g[e]; i1 = e; }
  if (lane == 0) {
    topi[t] = make_int2(i0, i1);
    topv[t] = make_float2(v0, v1);
#pragma unroll
    for (int e = 0; e < NE; ++e) gsh[w][e] = g[e];
  }
  __syncthreads();
  if (tid < NE)
    blkimp[blockIdx.x * NE + tid] =
        gsh[0][tid] + gsh[1][tid] + gsh[2][tid] + gsh[3][tid];
}

// ---------------------------------------------- FCFS dispatch + losses -----
__global__ __launch_bounds__(256) void dispatch_kernel(
    const int2* __restrict__ topi, const float2* __restrict__ topv,
    const float* __restrict__ blkimp, int2* __restrict__ posmj,
    float2* __restrict__ wmaj, float* __restrict__ tail) {
  __shared__ unsigned char eid[2 * T_TOK];
  __shared__ unsigned short possm[2 * T_TOK];
  __shared__ int cnt_sh[NE];
  __shared__ float part[32][NE];
  int tid = threadIdx.x;
  for (int i = tid; i < T_TOK; i += 256) {
    int2 ti = topi[i];
    eid[i] = (unsigned char)ti.x;
    eid[T_TOK + i] = (unsigned char)ti.y;
  }
  __syncthreads();
  if (tid < 64) {
    int lane = tid;
    unsigned long long low = (1ull << lane) - 1ull;
    int c0 = 0, c1 = 0, c2 = 0, c3 = 0, c4 = 0, c5 = 0, c6 = 0, c7 = 0;
    for (int base = 0; base < 2 * T_TOK; base += 64) {
      int e = eid[base + lane];
      unsigned long long m0 = __ballot(e == 0);
      unsigned long long m1 = __ballot(e == 1);
      unsigned long long m2 = __ballot(e == 2);
      unsigned long long m3 = __ballot(e == 3);
      unsigned long long m4 = __ballot(e == 4);
      unsigned long long m5 = __ballot(e == 5);
      unsigned long long m6 = __ballot(e == 6);
      unsigned long long m7 = __ballot(e == 7);
      int rank = 0;
      if (e == 0) rank = c0 + __popcll(m0 & low);
      if (e == 1) rank = c1 + __popcll(m1 & low);
      if (e == 2) rank = c2 + __popcll(m2 & low);
      if (e == 3) rank = c3 + __popcll(m3 & low);
      if (e == 4) rank = c4 + __popcll(m4 & low);
      if (e == 5) rank = c5 + __popcll(m5 & low);
      if (e == 6) rank = c6 + __popcll(m6 & low);
      if (e == 7) rank = c7 + __popcll(m7 & low);
      possm[base + lane] = (unsigned short)((rank < CCAP) ? rank : CCAP);
      c0 += __popcll(m0); c1 += __popcll(m1); c2 += __popcll(m2);
      c3 += __popcll(m3); c4 += __popcll(m4); c5 += __popcll(m5);
      c6 += __popcll(m6); c7 += __popcll(m7);
    }
    if (lane == 0) {
      cnt_sh[0] = c0; cnt_sh[1] = c1; cnt_sh[2] = c2; cnt_sh[3] = c3;
      cnt_sh[4] = c4; cnt_sh[5] = c5; cnt_sh[6] = c6; cnt_sh[7] = c7;
    }
  }
  __syncthreads();
  for (int t = tid; t < T_TOK; t += 256) {
    int p0 = possm[t], p1 = possm[T_TOK + t];
    float2 tv = topv[t];
    float w0 = (p0 < CCAP) ? tv.x : 0.0f;
    float w1 = (p1 < CCAP) ? tv.y : 0.0f;
    float s = w0 + w1;
    if (s > 0.0f) { w0 /= s; w1 /= s; }
    posmj[t] = make_int2(p0, p1);
    wmaj[t] = make_float2(w0, w1);
  }
  {
    int sl = tid >> 3, e8 = tid & 7;
    float s = 0.f;
    for (int b = sl; b < 2048; b += 32) s += blkimp[b * NE + e8];
    part[sl][e8] = s;
  }
  __syncthreads();
  if (tid == 0) {
    float imp[NE], te[NE];
    for (int e = 0; e < NE; ++e) {
      float s = 0.f;
      for (int j = 0; j < 32; ++j) s += part[j][e];
      imp[e] = s;
      int c = cnt_sh[e];
      te[e] = (float)(c < CCAP ? c : CCAP);
    }
    float mi = 0.f, mt = 0.f;
    for (int e = 0; e < NE; ++e) { mi += imp[e]; mt += te[e]; }
    mi *= 0.125f; mt *= 0.125f;
    float vi = 0.f, vt = 0.f;
    for (int e = 0; e < NE; ++e) {
      vi += (imp[e] - mi) * (imp[e] - mi);
      vt += (te[e] - mt) * (te[e] - mt);
    }
    vi *= 0.125f; vt *= 0.125f;
    float ai = sqrtf(vi) / (mi + 1e-6f);
    float at = sqrtf(vt) / (mt + 1e-6f);
    tail[0] = 0.5f * (ai * ai + at * at);
    tail[1] = at * at;
  }
}

// --------------------------------------------------------------- scatter ---
__global__ __launch_bounds__(256) void scatter_kernel(
    const float* __restrict__ x, const int2* __restrict__ topi,
    const int2* __restrict__ posmj, unsigned short* __restrict__ ein) {
  int tid = threadIdx.x;
  int gid = blockIdx.x * 4 + (tid >> 6);
  int lane = tid & 63;
  int t = gid >> 1, k = gid & 1;
  int2 pp = posmj[t];
  int p = k ? pp.y : pp.x;
  if (p >= CCAP) return;
  int2 ii = topi[t];
  int e = k ? ii.y : ii.x;
  const float4* src = (const float4*)(x + (size_t)t * DDIM);
  unsigned short* dst = ein + ((size_t)e * CPAD + p) * DDIM;
#pragma unroll
  for (int j = 0; j < 4; ++j) {
    int c = j * 64 + lane;
    float4 v = src[c];
    ushort4v o;
    o.x = f2bf(v.x); o.y = f2bf(v.y); o.z = f2bf(v.z); o.w = f2bf(v.w);
    *(ushort4v*)(dst + (size_t)c * 4) = o;
  }
}

// ------------------------------------------------- weight transpose+cvt ----
__global__ __launch_bounds__(256) void transpose_cvt_kernel(
    const float* __restrict__ W, unsigned short* __restrict__ WT, int R,
    int Cc) {
  __shared__ unsigned short tile[64][72];
  int rt = R >> 6, ct = Cc >> 6;
  int per_e = rt * ct;
  int e = blockIdx.x / per_e;
  int rem = blockIdx.x % per_e;
  int tr = rem % rt, tc = rem / rt;
  int r0 = tr << 6, c0 = tc << 6;
  const float* We = W + (size_t)e * R * Cc;
  unsigned short* WTe = WT + (size_t)e * R * Cc;
  int tid = threadIdx.x;
  {
    int rl = tid >> 2, cb = (tid & 3) << 4;
    const float* src = We + (size_t)(r0 + rl) * Cc + c0 + cb;
#pragma unroll
    for (int j = 0; j < 16; j += 4) {
      float4 v = *(const float4*)(src + j);
      tile[rl][cb + j + 0] = f2bf(v.x);
      tile[rl][cb + j + 1] = f2bf(v.y);
      tile[rl][cb + j + 2] = f2bf(v.z);
      tile[rl][cb + j + 3] = f2bf(v.w);
    }
  }
  __syncthreads();
  {
    int cl = tid >> 2, rb = (tid & 3) << 4;
    unsigned short* dst = WTe + (size_t)(c0 + cl) * R + r0 + rb;
#pragma unroll
    for (int j = 0; j < 16; j += 4) {
      ushort4v o;
      o.x = tile[rb + j + 0][cl];
      o.y = tile[rb + j + 1][cl];
      o.z = tile[rb + j + 2][cl];
      o.w = tile[rb + j + 3][cl];
      *(ushort4v*)(dst + j) = o;
    }
  }
}

// ------------------------------------------------ 256x256 8-phase GEMM -----
// A: (E, M, Kz) bf16 row-major; B: (E, N, Kz) bf16 (B^T, K contiguous).
// Out (E,M,N) bf16. 8 waves (2Mx4N), BK=64 (2 kk of 32), 4 phases/K-tile.
// All LDS fragment reads are inline-asm ds_read_b128 (opaque to the
// compiler's waitcnt pass -> no auto vmcnt(0) drains); waits are bare
// volatile asm: lgkmcnt(0)+sched_barrier(0) post-barrier, counted vmcnt(8)
// at phase1/phase3 ends (ledger: 4 stage-points x 2 loads in flight).
template <bool GELU>
__global__ __launch_bounds__(512, 2) void gemm256_kernel(
    const unsigned short* __restrict__ A, const unsigned short* __restrict__ B,
    const float* __restrict__ bias, unsigned short* __restrict__ Out0,
    unsigned short* __restrict__ Out1, int M, int N, int Kz, int Ksub, int NT,
    int mt, int nt) {
  __shared__ __align__(16) char smem[131072];
  int nwg = gridDim.x;
  int bid = blockIdx.x;
  int swz = (bid & 7) * (nwg >> 3) + (bid >> 3);  // XCD-aware (nwg % 8 == 0)
  int bm = swz % mt;
  int r = swz / mt;
  int bn = r % nt;
  int r2 = r / nt;
  int e = r2 & 7;
  int ks = r2 >> 3;
  unsigned short* Outp = ks ? Out1 : Out0;
  int koff = ks * Ksub;

  int tid = threadIdx.x;
  int w = tid >> 6, lane = tid & 63;
  int wm = w >> 2, wn = w & 3;
  int fr = lane & 15, g = lane >> 4;
  size_t Kzs = (size_t)Kz;
  const char* Ab = (const char*)(A + ((size_t)e * M + (size_t)bm * 256) * Kzs + koff);
  const char* Bb = (const char*)(B + ((size_t)e * N + (size_t)bn * 256) * Kzs + koff);

  size_t ro0 = (size_t)(w * 16 + fr) * Kzs * 2 + (size_t)g * 16;
  size_t ro1 = ro0 + (size_t)128 * Kzs * 2;
  int ld0 = (w << 10) + lane * 16;
  int ld1 = ((8 + w) << 10) + lane * 16;

  // stage one 16KB half: [isB(64KB)][buf(32KB)][kh(16KB)][row16(1KB)][lane*16]
  auto stage = [&](const char* gb, int buf, int isB, int kh) {
    int base = (isB << 16) + (buf << 15) + (kh << 14);
    GLOAD_LDS16(gb + ro0 + kh * 64, smem + base + ld0);
    GLOAD_LDS16(gb + ro1 + kh * 64, smem + base + ld1);
  };

  unsigned sbase =
      (unsigned)(unsigned long long)(__attribute__((address_space(3))) char*)smem;
  unsigned l16 = (unsigned)(lane * 16);
  unsigned am = sbase + (unsigned)((wm * 8) << 10) + l16;        // A rows 0-3
  unsigned bnr = sbase + 65536u + (unsigned)((wn * 4) << 10) + l16;  // B

  f32x4 acc[8][4] = {};
  short8v Af[4], Bk[4];

#define MM16(RO)                                                           \
  do {                                                                     \
    __builtin_amdgcn_s_setprio(1);                                         \
    _Pragma("unroll") for (int m_ = 0; m_ < 4; ++m_)                       \
        _Pragma("unroll") for (int n_ = 0; n_ < 4; ++n_)                   \
            acc[RO + m_][n_] = __builtin_amdgcn_mfma_f32_16x16x32_bf16(    \
                Af[m_], Bk[n_], acc[RO + m_][n_], 0, 0, 0);                \
    __builtin_amdgcn_s_setprio(0);                                         \
    __builtin_amdgcn_sched_barrier(0);                                     \
  } while (0)

  // prologue: t0 kh0, t0 kh1, t1 kh0 (age order for the vmcnt ledger)
  stage(Ab, 0, 0, 0); stage(Bb, 0, 1, 0);
  stage(Ab, 0, 0, 1); stage(Bb, 0, 1, 1);
  stage(Ab + 128, 1, 0, 0); stage(Bb + 128, 1, 1, 0);
  asm volatile("s_waitcnt vmcnt(8)");  // t0 kh0 landed (own share)
  BAR();                               // collective confirm

  for (int t = 0; t < NT; ++t) {
    int c = t & 1, cn = c ^ 1;
    unsigned cb = (unsigned)(c << 15);
    const char* At1 = Ab + (size_t)(t + 1) * 128;
    const char* Bt1 = Bb + (size_t)(t + 1) * 128;
    const char* At2 = Ab + (size_t)(t + 2) * 128;
    const char* Bt2 = Bb + (size_t)(t + 2) * 128;
    // ---- p0: kk0, acc rows 0-3 ------------------------------------------
#pragma unroll
    for (int n = 0; n < 4; ++n) Bk[n] = ds_read128(bnr + cb + (n << 10));
#pragma unroll
    for (int m = 0; m < 4; ++m) Af[m] = ds_read128(am + cb + (m << 10));
    if (t + 1 < NT) stage(At1, cn, 0, 1);
    BAR();
    WLGKM0();
    MM16(0);
    BAR();
    // ---- p1: kk0, acc rows 4-7 (Bk reused) ------------------------------
#pragma unroll
    for (int m = 0; m < 4; ++m)
      Af[m] = ds_read128(am + cb + ((4 + m) << 10));
    if (t + 1 < NT) stage(Bt1, cn, 1, 1);
    BAR();
    WLGKM0();
    MM16(4);
    if (t + 1 < NT) asm volatile("s_waitcnt vmcnt(8)");
    else            asm volatile("s_waitcnt vmcnt(0)");
    BAR();  // collective: kh1(t) staged
    // ---- p2: kk1, acc rows 0-3 ------------------------------------------
#pragma unroll
    for (int n = 0; n < 4; ++n)
      Bk[n] = ds_read128(bnr + cb + 16384u + (n << 10));
#pragma unroll
    for (int m = 0; m < 4; ++m)
      Af[m] = ds_read128(am + cb + 16384u + (m << 10));
    if (t + 2 < NT) stage(At2, c, 0, 0);
    BAR();
    WLGKM0();
    MM16(0);
    BAR();
    // ---- p3: kk1, acc rows 4-7 ------------------------------------------
#pragma unroll
    for (int m = 0; m < 4; ++m)
      Af[m] = ds_read128(am + cb + 16384u + ((4 + m) << 10));
    if (t + 2 < NT) stage(Bt2, c, 1, 0);
    BAR();
    WLGKM0();
    MM16(4);
    if (t + 2 < NT)      asm volatile("s_waitcnt vmcnt(8)");
    else if (t + 1 < NT) asm volatile("s_waitcnt vmcnt(4)");
    else                 asm volatile("s_waitcnt vmcnt(0)");
    BAR();  // collective: kh0(t+1) staged
  }
#undef MM16

  // ---- epilogue: bias/GELU -> per-wave LDS bounce -> coalesced stores ----
  float bv[4];
#pragma unroll
  for (int n = 0; n < 4; ++n)
    bv[n] = (ks == 0)
                ? bias[(size_t)e * N + (size_t)bn * 256 + wn * 64 + n * 16 + fr]
                : 0.0f;
  char* wreg = smem + w * 16384;  // [128 rows][64 cols] u16, row stride 128B
#pragma unroll
  for (int m = 0; m < 8; ++m)
#pragma unroll
    for (int n = 0; n < 4; ++n)
#pragma unroll
      for (int j = 0; j < 4; ++j) {
        float v = acc[m][n][j] + bv[n];
        if (GELU) v = 0.5f * v * (1.0f + erff(v * 0.70710678118654752f));
        int rl = m * 16 + g * 4 + j;
        *(unsigned short*)(wreg + rl * 128 + (n * 16 + fr) * 2) = f2bf(v);
      }
  unsigned short* Oe = Outp +
                       ((size_t)e * M + (size_t)bm * 256 + (size_t)wm * 128) * N +
                       (size_t)bn * 256 + (size_t)wn * 64;
#pragma unroll
  for (int pass = 0; pass < 16; ++pass) {
    int rr = pass * 8 + (lane >> 3);
    int ch = lane & 7;
    short8v vv = *(const short8v*)(wreg + rr * 128 + ch * 16);
    *(short8v*)(Oe + (size_t)rr * N + ch * 8) = vv;
  }
}

// ---------------------------------------------------------------- gather ---
__global__ __launch_bounds__(256) void gather_kernel(
    const unsigned short* __restrict__ obufA,
    const unsigned short* __restrict__ obufB, const int2* __restrict__ topi,
    const int2* __restrict__ posmj, const float2* __restrict__ wmaj,
    float* __restrict__ y) {
  int tid = threadIdx.x;
  int w = tid >> 6, lane = tid & 63;
  int t = blockIdx.x * 4 + w;
  int2 pp = posmj[t];
  int2 ii = topi[t];
  float2 ww = wmaj[t];
  float* yr = y + (size_t)t * DDIM;
  size_t o0 = ((size_t)ii.x * CPAD + pp.x) * DDIM;
  size_t o1 = ((size_t)ii.y * CPAD + pp.y) * DDIM;
  bool v0 = pp.x < CCAP, v1 = pp.y < CCAP;
#pragma unroll
  for (int j = 0; j < 4; ++j) {
    int c = j * 64 + lane;
    float ax = 0.f, ay = 0.f, az = 0.f, aw = 0.f;
    if (v0) {
      ushort4v a = *(const ushort4v*)(obufA + o0 + (size_t)c * 4);
      ushort4v b = *(const ushort4v*)(obufB + o0 + (size_t)c * 4);
      ax += ww.x * (bf2f(a.x) + bf2f(b.x));
      ay += ww.x * (bf2f(a.y) + bf2f(b.y));
      az += ww.x * (bf2f(a.z) + bf2f(b.z));
      aw += ww.x * (bf2f(a.w) + bf2f(b.w));
    }
    if (v1) {
      ushort4v a = *(const ushort4v*)(obufA + o1 + (size_t)c * 4);
      ushort4v b = *(const ushort4v*)(obufB + o1 + (size_t)c * 4);
      ax += ww.y * (bf2f(a.x) + bf2f(b.x));
      ay += ww.y * (bf2f(a.y) + bf2f(b.y));
      az += ww.y * (bf2f(a.z) + bf2f(b.z));
      aw += ww.y * (bf2f(a.w) + bf2f(b.w));
    }
    ((float4*)yr)[c] = make_float4(ax, ay, az, aw);
  }
}

// ---------------------------------------------------------------------------
extern "C" void kernel_launch(void* const* d_in, const int* in_sizes, int n_in,
                              void* d_out, int out_size, void* d_ws,
                              size_t ws_size, hipStream_t stream) {
  (void)in_sizes; (void)n_in; (void)out_size; (void)ws_size;
  const float* x = (const float*)d_in[0];
  const float* Wg = (const float*)d_in[1];
  const float* W1 = (const float*)d_in[2];
  const float* b1 = (const float*)d_in[3];
  const float* W2 = (const float*)d_in[4];
  const float* b2 = (const float*)d_in[5];
  float* out = (float*)d_out;

  char* ws = (char*)d_ws;
  size_t off = 0;
  auto alloc = [&](size_t b) {
    char* p = ws + off;
    off += (b + 255) & ~(size_t)255;
    return p;
  };
  unsigned short* ein = (unsigned short*)alloc((size_t)NE * CPAD * DDIM * 2);
  unsigned short* hbuf = (unsigned short*)alloc((size_t)NE * CPAD * HDIM * 2);
  unsigned short* obuf = (unsigned short*)alloc((size_t)NE * CPAD * DDIM * 2);
  unsigned short* w1t = (unsigned short*)alloc((size_t)NE * HDIM * DDIM * 2);
  unsigned short* w2t = (unsigned short*)alloc((size_t)NE * DDIM * HDIM * 2);
  int2* topi = (int2*)alloc(T_TOK * sizeof(int2));
  float2* topv = (float2*)alloc(T_TOK * sizeof(float2));
  int2* posmj = (int2*)alloc(T_TOK * sizeof(int2));
  float2* wmaj = (float2*)alloc(T_TOK * sizeof(float2));
  float* blkimp = (float*)alloc(2048 * NE * sizeof(float));

  transpose_cvt_kernel<<<NE * (DDIM / 64) * (HDIM / 64), 256, 0, stream>>>(
      W1, w1t, DDIM, HDIM);
  transpose_cvt_kernel<<<NE * (HDIM / 64) * (DDIM / 64), 256, 0, stream>>>(
      W2, w2t, HDIM, DDIM);
  router_kernel<<<T_TOK / 4, 256, 0, stream>>>(x, Wg, topi, topv, blkimp);
  dispatch_kernel<<<1, 256, 0, stream>>>(topi, topv, blkimp, posmj, wmaj,
                                         out + (size_t)T_TOK * DDIM);
  scatter_kernel<<<(2 * T_TOK) / 4, 256, 0, stream>>>(x, topi, posmj, ein);

  // gemm1: (E,2304,1024) x (E,4096,1024)^T -> hbuf (E,2304,4096), GELU+b1
  gemm256_kernel<true><<<NE * 9 * 16, 512, 0, stream>>>(
      ein, w1t, b1, hbuf, hbuf, CPAD, HDIM, DDIM, DDIM, DDIM / 64, 9, 16);
  // gemm2: (E,2304,4096) x (E,1024,4096)^T -> obuf (+b2) and ein (split-K)
  gemm256_kernel<false><<<NE * 9 * 4 * 2, 512, 0, stream>>>(
      hbuf, w2t, b2, obuf, ein, CPAD, DDIM, HDIM, HDIM / 2, HDIM / 128, 9, 4);

  gather_kernel<<<T_TOK / 4, 256, 0, stream>>>(obuf, ein, topi, posmj, wmaj,
                                               out);
}